// Round 2
// baseline (226.639 us; speedup 1.0000x reference)
//
#include <hip/hip_runtime.h>

#define LOG2E 1.4426950408889634f

typedef __attribute__((ext_vector_type(4))) float f32x4;
typedef __attribute__((ext_vector_type(4))) short s16x4;
typedef __attribute__((ext_vector_type(8))) short s16x8;
typedef __attribute__((ext_vector_type(4))) __bf16 bf16x4;
typedef __attribute__((ext_vector_type(8))) __bf16 bf16x8;

// B=2 S=2048 H=16 D=64, fp32 in/out.
#define SS 2048
#define HH 16
#define DD 64
#define HSZ (HH * DD)

// ---- prep 1: K [B,S,H,D] f32 -> Kb [B,H,S,D] bf16 ------------------------
__global__ __launch_bounds__(256) void prep_k(const float* __restrict__ Kg,
                                              short* __restrict__ Kb) {
  int idx = blockIdx.x * 256 + threadIdx.x;  // 1,048,576 quads
  int d4 = idx & 15, h = (idx >> 4) & 15, s = (idx >> 8) & 2047, b = idx >> 19;
  f32x4 v = *(const f32x4*)(Kg + ((((size_t)b * SS + s) * HH + h) << 6) + (d4 << 2));
  bf16x4 o;
#pragma unroll
  for (int j = 0; j < 4; ++j) o[j] = (__bf16)v[j];
  *(s16x4*)(Kb + ((((size_t)b * HH + h) * SS + s) << 6) + (d4 << 2)) =
      __builtin_bit_cast(s16x4, o);
}

// ---- prep 2: V [B,S,H,D] f32 -> VT [B,H,D,S] bf16 (transpose) ------------
__global__ __launch_bounds__(256) void prep_vt(const float* __restrict__ Vg,
                                               short* __restrict__ VT) {
  __shared__ short tile[64][68];  // stride 68 shorts: keeps 8B alignment
  const int tid = threadIdx.x;
  const int bh = blockIdx.x >> 5, stile = blockIdx.x & 31;
  const int b = bh >> 4, h = bh & 15;
#pragma unroll
  for (int p = 0; p < 4; ++p) {
    int s = (tid >> 4) + p * 16, d4 = tid & 15;
    f32x4 v = *(const f32x4*)(Vg + ((((size_t)b * SS + stile * 64 + s) * HH + h) << 6) + (d4 << 2));
    bf16x4 o;
#pragma unroll
    for (int j = 0; j < 4; ++j) o[j] = (__bf16)v[j];
    *(s16x4*)(&tile[s][d4 << 2]) = __builtin_bit_cast(s16x4, o);
  }
  __syncthreads();
#pragma unroll
  for (int p = 0; p < 4; ++p) {
    int d = (tid >> 4) + p * 16, s0 = (tid & 15) << 2;
    s16x4 o;
#pragma unroll
    for (int j = 0; j < 4; ++j) o[j] = tile[s0 + j][d];
    *(s16x4*)(VT + (((size_t)bh * 64 + d) * SS) + stile * 64 + s0) = o;
  }
}

// ---- main: flash attention, bf16 K/V from ws -----------------------------
// One wave per 16 q-rows. S^T = K*Q^T (16x16x32 mfma) so the P registers
// feed PV's B operand (OT = V^T*P, 16x16x16) with zero cross-lane traffic.
// Softmax amortized over 64-key groups; rescale deferred (THR=8 in log2).
__global__ __launch_bounds__(256) void attn_fwd2(
    const float* __restrict__ Qg, const short* __restrict__ Kb,
    const short* __restrict__ VTb, float* __restrict__ Og)
{
  const int tid  = threadIdx.x;
  const int lane = tid & 63;
  const int lm   = lane & 15;
  const int g    = lane >> 4;
  const int w    = tid >> 6;

  const int bh = blockIdx.x;  // 0..31
  const int t  = ((gridDim.y - 1 - blockIdx.y) << 2) | w;  // heavy-first
  const int qb = t << 4;

  const short* kbase = Kb  + (size_t)bh * SS * DD;
  const short* vtb   = VTb + (size_t)bh * DD * SS;
  const size_t qbase = (size_t)(bh >> 4) * SS * HSZ + (size_t)(bh & 15) * DD;

  // Q frag (B operand of S^T, K=32): d = c*32 + g*8 + j, pre-scaled
  s16x8 qf[2];
  {
    const float* qp = Qg + qbase + (size_t)(qb + lm) * HSZ + g * 8;
    const float qs = 0.125f * LOG2E;
#pragma unroll
    for (int c = 0; c < 2; ++c) {
      f32x4 a = *(const f32x4*)(qp + c * 32);
      f32x4 b2 = *(const f32x4*)(qp + c * 32 + 4);
      bf16x8 bv;
#pragma unroll
      for (int j = 0; j < 4; ++j) {
        bv[j] = (__bf16)(a[j] * qs);
        bv[4 + j] = (__bf16)(b2[j] * qs);
      }
      qf[c] = __builtin_bit_cast(s16x8, bv);
    }
  }

  f32x4 oacc[4] = {{0,0,0,0},{0,0,0,0},{0,0,0,0},{0,0,0,0}};
  float m = -1e30f, l = 0.0f;

  const short* kp  = kbase + (size_t)lm * DD + g * 8;  // + key*64 later
  const short* vp0 = vtb + (size_t)lm * SS + g * 4;    // + nb*16*S + key

  const int ng = t >> 2;  // full 64-key groups

  for (int j = 0; j < ng; ++j) {
    const int kb4 = j << 6;
    // ---- S^T: 4 subtiles x (2 mfma 16x16x32)
    f32x4 st[4];
#pragma unroll
    for (int su = 0; su < 4; ++su) {
      const short* ka = kp + (size_t)(kb4 + su * 16) * DD;
      f32x4 acc = {0, 0, 0, 0};
#pragma unroll
      for (int c = 0; c < 2; ++c)
        acc = __builtin_amdgcn_mfma_f32_16x16x32_bf16(
            *(const s16x8*)(ka + c * 32), qf[c], acc, 0, 0, 0);
      st[su] = acc;
    }
    // ---- group softmax (stats lane-local in q = lm)
    float tmax = -1e30f;
#pragma unroll
    for (int su = 0; su < 4; ++su)
#pragma unroll
      for (int r = 0; r < 4; ++r) tmax = fmaxf(tmax, st[su][r]);
    tmax = fmaxf(tmax, __shfl_xor(tmax, 16));
    tmax = fmaxf(tmax, __shfl_xor(tmax, 32));
    if (!__all(tmax <= m + 8.0f)) {  // deferred rescale
      const float mnew = fmaxf(m, tmax);
      const float fsc = exp2f(m - mnew);
#pragma unroll
      for (int nb = 0; nb < 4; ++nb)
#pragma unroll
        for (int r = 0; r < 4; ++r) oacc[nb][r] *= fsc;
      l *= fsc;
      m = mnew;
    }
    float ps[4][4];
    float tsum = 0.0f;
#pragma unroll
    for (int su = 0; su < 4; ++su)
#pragma unroll
      for (int r = 0; r < 4; ++r) {
        float p = exp2f(st[su][r] - m);
        ps[su][r] = p;
        tsum += p;
      }
    tsum += __shfl_xor(tsum, 16);
    tsum += __shfl_xor(tsum, 32);
    l += tsum;
    // ---- PV: per subtile, P is the B operand directly (key = 4g+r)
#pragma unroll
    for (int su = 0; su < 4; ++su) {
      bf16x4 pb;
#pragma unroll
      for (int r = 0; r < 4; ++r) pb[r] = (__bf16)ps[su][r];
      const s16x4 pf = __builtin_bit_cast(s16x4, pb);
      const short* vpp = vp0 + kb4 + su * 16;
#pragma unroll
      for (int nb = 0; nb < 4; ++nb) {
        s16x4 vv = *(const s16x4*)(vpp + (size_t)nb * 16 * SS);
        oacc[nb] = __builtin_amdgcn_mfma_f32_16x16x16bf16_1k(
            vv, pf, oacc[nb], 0, 0, 0);
      }
    }
  }

  // ---- tail: subtiles 4*ng .. t, diagonal mask on subtile t
  for (int sub = ng << 2; sub <= t; ++sub) {
    const short* ka = kp + (size_t)sub * 16 * DD;
    f32x4 stv = {0, 0, 0, 0};
#pragma unroll
    for (int c = 0; c < 2; ++c)
      stv = __builtin_amdgcn_mfma_f32_16x16x32_bf16(
          *(const s16x8*)(ka + c * 32), qf[c], stv, 0, 0, 0);
    if (sub == t) {
#pragma unroll
      for (int r = 0; r < 4; ++r)
        if (g * 4 + r > lm) stv[r] = -1e30f;
    }
    float tmax = fmaxf(fmaxf(stv[0], stv[1]), fmaxf(stv[2], stv[3]));
    tmax = fmaxf(tmax, __shfl_xor(tmax, 16));
    tmax = fmaxf(tmax, __shfl_xor(tmax, 32));
    if (!__all(tmax <= m + 8.0f)) {
      const float mnew = fmaxf(m, tmax);
      const float fsc = exp2f(m - mnew);
#pragma unroll
      for (int nb = 0; nb < 4; ++nb)
#pragma unroll
        for (int r = 0; r < 4; ++r) oacc[nb][r] *= fsc;
      l *= fsc;
      m = mnew;
    }
    f32x4 p;
    float tsum = 0.0f;
#pragma unroll
    for (int r = 0; r < 4; ++r) {
      p[r] = exp2f(stv[r] - m);
      tsum += p[r];
    }
    tsum += __shfl_xor(tsum, 16);
    tsum += __shfl_xor(tsum, 32);
    l += tsum;
    bf16x4 pb;
#pragma unroll
    for (int r = 0; r < 4; ++r) pb[r] = (__bf16)p[r];
    const s16x4 pf = __builtin_bit_cast(s16x4, pb);
    const short* vpp = vp0 + sub * 16;
#pragma unroll
    for (int nb = 0; nb < 4; ++nb) {
      s16x4 vv = *(const s16x4*)(vpp + (size_t)nb * 16 * SS);
      oacc[nb] = __builtin_amdgcn_mfma_f32_16x16x16bf16_1k(
          vv, pf, oacc[nb], 0, 0, 0);
    }
  }

  // ---- store: lane holds out[q=qb+lm][d = nb*16 + 4g + r]
  const float inv = 1.0f / l;
  float* op = Og + qbase + (size_t)(qb + lm) * HSZ + g * 4;
#pragma unroll
  for (int nb = 0; nb < 4; ++nb) {
    f32x4 o = oacc[nb];
#pragma unroll
    for (int r = 0; r < 4; ++r) o[r] *= inv;
    *(f32x4*)(op + nb * 16) = o;
  }
}

// ---- fallback (round-1 kernel) if ws too small ---------------------------
__global__ __launch_bounds__(256) void attn_fwd(
    const float* __restrict__ Qg, const float* __restrict__ Kg,
    const float* __restrict__ Vg, float* __restrict__ Og)
{
  const int tid  = threadIdx.x;
  const int lane = tid & 63;
  const int lm   = lane & 15;
  const int g    = lane >> 4;
  const int w    = tid >> 6;
  const int bh = blockIdx.x;
  const int b  = bh >> 4;
  const int h  = bh & 15;
  const int t  = ((gridDim.y - 1 - blockIdx.y) << 2) | w;
  const int qb = t << 4;
  const size_t base = (size_t)b * SS * HSZ + (size_t)h * DD;
  s16x4 qf[4];
  {
    const float* qp = Qg + base + (size_t)(qb + lm) * HSZ + g * 4;
    const float qs = 0.125f * LOG2E;
#pragma unroll
    for (int c = 0; c < 4; ++c) {
      f32x4 qv = *(const f32x4*)(qp + c * 16);
      bf16x4 bv;
#pragma unroll
      for (int j = 0; j < 4; ++j) bv[j] = (__bf16)(qv[j] * qs);
      qf[c] = __builtin_bit_cast(s16x4, bv);
    }
  }
  f32x4 oacc[4] = {{0,0,0,0},{0,0,0,0},{0,0,0,0},{0,0,0,0}};
  float m = -1e30f, lsum = 0.0f;
  const float* kp = Kg + base + (size_t)lm * HSZ + g * 4;
  const float* vp = Vg + base + (size_t)(g * 4) * HSZ + lm;
  for (int kt = 0; kt <= t; ++kt) {
    const float* kpp = kp + (size_t)(kt << 4) * HSZ;
    f32x4 st = {0, 0, 0, 0};
#pragma unroll
    for (int c = 0; c < 4; ++c) {
      f32x4 kv = *(const f32x4*)(kpp + c * 16);
      bf16x4 bv;
#pragma unroll
      for (int j = 0; j < 4; ++j) bv[j] = (__bf16)kv[j];
      st = __builtin_amdgcn_mfma_f32_16x16x16bf16_1k(
               __builtin_bit_cast(s16x4, bv), qf[c], st, 0, 0, 0);
    }
    if (kt == t) {
#pragma unroll
      for (int r = 0; r < 4; ++r)
        if (g * 4 + r > lm) st[r] = -1e30f;
    }
    float tmax = fmaxf(fmaxf(st[0], st[1]), fmaxf(st[2], st[3]));
    tmax = fmaxf(tmax, __shfl_xor(tmax, 16));
    tmax = fmaxf(tmax, __shfl_xor(tmax, 32));
    const float mnew = fmaxf(m, tmax);
    const float fsc  = exp2f(m - mnew);
    f32x4 p;
#pragma unroll
    for (int r = 0; r < 4; ++r) p[r] = exp2f(st[r] - mnew);
    float tsum = (p[0] + p[1]) + (p[2] + p[3]);
    tsum += __shfl_xor(tsum, 16);
    tsum += __shfl_xor(tsum, 32);
    lsum = lsum * fsc + tsum;
    m = mnew;
#pragma unroll
    for (int nb = 0; nb < 4; ++nb)
#pragma unroll
      for (int r = 0; r < 4; ++r) oacc[nb][r] *= fsc;
    bf16x4 pb;
#pragma unroll
    for (int r = 0; r < 4; ++r) pb[r] = (__bf16)p[r];
    const s16x4 pf = __builtin_bit_cast(s16x4, pb);
    const float* vpp = vp + (size_t)(kt << 4) * HSZ;
#pragma unroll
    for (int nb = 0; nb < 4; ++nb) {
      bf16x4 vv;
#pragma unroll
      for (int j = 0; j < 4; ++j)
        vv[j] = (__bf16)vpp[(size_t)j * HSZ + nb * 16];
      oacc[nb] = __builtin_amdgcn_mfma_f32_16x16x16bf16_1k(
                     __builtin_bit_cast(s16x4, vv), pf, oacc[nb], 0, 0, 0);
    }
  }
  const float inv = 1.0f / lsum;
  float* op = Og + base + (size_t)(qb + lm) * HSZ + g * 4;
#pragma unroll
  for (int nb = 0; nb < 4; ++nb) {
    f32x4 o = oacc[nb];
#pragma unroll
    for (int r = 0; r < 4; ++r) o[r] *= inv;
    *(f32x4*)(op + nb * 16) = o;
  }
}

extern "C" void kernel_launch(void* const* d_in, const int* in_sizes, int n_in,
                              void* d_out, int out_size, void* d_ws, size_t ws_size,
                              hipStream_t stream) {
  const float* q = (const float*)d_in[0];
  const float* k = (const float*)d_in[1];
  const float* v = (const float*)d_in[2];
  float* o = (float*)d_out;
  const size_t elems = (size_t)2 * HH * SS * DD;     // 4,194,304 per tensor
  const size_t need  = 2 * elems * sizeof(short);    // Kb + VT, 16.8 MB
  if (ws_size >= need) {
    short* Kb = (short*)d_ws;
    short* VT = Kb + elems;
    prep_k<<<4096, 256, 0, stream>>>(k, Kb);
    prep_vt<<<1024, 256, 0, stream>>>(v, VT);
    attn_fwd2<<<dim3(32, 32), 256, 0, stream>>>(q, Kb, VT, o);
  } else {
    attn_fwd<<<dim3(32, 32), 256, 0, stream>>>(q, k, v, o);
  }
}

// Round 3
// 213.475 us; speedup vs baseline: 1.0617x; 1.0617x over previous
//
#include <hip/hip_runtime.h>

#define LOG2E 1.4426950408889634f

typedef __attribute__((ext_vector_type(4))) float f32x4;
typedef __attribute__((ext_vector_type(4))) short s16x4;
typedef __attribute__((ext_vector_type(8))) short s16x8;
typedef __attribute__((ext_vector_type(4))) __bf16 bf16x4;
typedef __attribute__((ext_vector_type(8))) __bf16 bf16x8;

// B=2 S=2048 H=16 D=64, fp32 in/out.
#define SS 2048
#define HH 16
#define DD 64
#define HSZ (HH * DD)

// ---- prep 1: K [B,S,H,D] f32 -> Kb [B,H,S,D] bf16 ------------------------
__global__ __launch_bounds__(256) void prep_k(const float* __restrict__ Kg,
                                              short* __restrict__ Kb) {
  int idx = blockIdx.x * 256 + threadIdx.x;  // 1,048,576 quads
  int d4 = idx & 15, h = (idx >> 4) & 15, s = (idx >> 8) & 2047, b = idx >> 19;
  f32x4 v = *(const f32x4*)(Kg + ((((size_t)b * SS + s) * HH + h) << 6) + (d4 << 2));
  bf16x4 o;
#pragma unroll
  for (int j = 0; j < 4; ++j) o[j] = (__bf16)v[j];
  *(s16x4*)(Kb + ((((size_t)b * HH + h) * SS + s) << 6) + (d4 << 2)) =
      __builtin_bit_cast(s16x4, o);
}

// ---- prep 2: V [B,S,H,D] f32 -> VT [B,H,D,S] bf16 (transpose) ------------
__global__ __launch_bounds__(256) void prep_vt(const float* __restrict__ Vg,
                                               short* __restrict__ VT) {
  __shared__ short tile[64][68];
  const int tid = threadIdx.x;
  const int bh = blockIdx.x >> 5, stile = blockIdx.x & 31;
  const int b = bh >> 4, h = bh & 15;
#pragma unroll
  for (int p = 0; p < 4; ++p) {
    int s = (tid >> 4) + p * 16, d4 = tid & 15;
    f32x4 v = *(const f32x4*)(Vg + ((((size_t)b * SS + stile * 64 + s) * HH + h) << 6) + (d4 << 2));
    bf16x4 o;
#pragma unroll
    for (int j = 0; j < 4; ++j) o[j] = (__bf16)v[j];
    *(s16x4*)(&tile[s][d4 << 2]) = __builtin_bit_cast(s16x4, o);
  }
  __syncthreads();
#pragma unroll
  for (int p = 0; p < 4; ++p) {
    int d = (tid >> 4) + p * 16, s0 = (tid & 15) << 2;
    s16x4 o;
#pragma unroll
    for (int j = 0; j < 4; ++j) o[j] = tile[s0 + j][d];
    *(s16x4*)(VT + (((size_t)bh * 64 + d) * SS) + stile * 64 + s0) = o;
  }
}

// ---- main: flash attention, register-pipelined, vote-deferred softmax ----
// One wave per 16 q-rows. S^T = K*Q^T (16x16x32) so P registers feed PV's
// B operand (OT = V^T*P, 16x16x16) with zero cross-lane traffic.
// 32-key groups; K double-buffered in regs (prefetch j+1 during j); V loads
// issued at iteration top, consumed after softmax. Steady-state softmax has
// NO shuffles: lane-local max + __all vote (deferred rescale, THR=8 in
// log2 => P <= 256, fine in fp32/bf16), l reduced once in the epilogue.
#define GBODY(KC, KN)                                                        \
  {                                                                          \
    const short* vj = vp0 + (j << 5);                                        \
    s16x4 vv00 = *(const s16x4*)(vj);                                        \
    s16x4 vv01 = *(const s16x4*)(vj + 16 * SS);                              \
    s16x4 vv02 = *(const s16x4*)(vj + 32 * SS);                              \
    s16x4 vv03 = *(const s16x4*)(vj + 48 * SS);                              \
    s16x4 vv10 = *(const s16x4*)(vj + 16);                                   \
    s16x4 vv11 = *(const s16x4*)(vj + 16 + 16 * SS);                         \
    s16x4 vv12 = *(const s16x4*)(vj + 16 + 32 * SS);                         \
    s16x4 vv13 = *(const s16x4*)(vj + 16 + 48 * SS);                         \
    const int jn = (j + 1 < ng) ? j + 1 : j;                                 \
    const short* kaN = kp + ((size_t)jn << 5) * DD;                          \
    KN[0] = *(const s16x8*)(kaN);                                            \
    KN[1] = *(const s16x8*)(kaN + 32);                                       \
    KN[2] = *(const s16x8*)(kaN + 16 * DD);                                  \
    KN[3] = *(const s16x8*)(kaN + 16 * DD + 32);                             \
    f32x4 st0 = {0, 0, 0, 0}, st1 = {0, 0, 0, 0};                            \
    st0 = __builtin_amdgcn_mfma_f32_16x16x32_bf16(KC[0], qf[0], st0, 0, 0, 0);\
    st0 = __builtin_amdgcn_mfma_f32_16x16x32_bf16(KC[1], qf[1], st0, 0, 0, 0);\
    st1 = __builtin_amdgcn_mfma_f32_16x16x32_bf16(KC[2], qf[0], st1, 0, 0, 0);\
    st1 = __builtin_amdgcn_mfma_f32_16x16x32_bf16(KC[3], qf[1], st1, 0, 0, 0);\
    float tmax = fmaxf(fmaxf(fmaxf(st0[0], st0[1]), fmaxf(st0[2], st0[3])),  \
                       fmaxf(fmaxf(st1[0], st1[1]), fmaxf(st1[2], st1[3]))); \
    if (!__all(tmax <= m + 8.0f)) {                                          \
      float tm = fmaxf(tmax, __shfl_xor(tmax, 16));                          \
      tm = fmaxf(tm, __shfl_xor(tm, 32));                                    \
      const float mnew = fmaxf(m, tm);                                       \
      const float fsc = exp2f(m - mnew);                                     \
      _Pragma("unroll") for (int nb = 0; nb < 4; ++nb)                       \
          _Pragma("unroll") for (int r = 0; r < 4; ++r) oacc[nb][r] *= fsc;  \
      lsum *= fsc;                                                           \
      m = mnew;                                                              \
    }                                                                        \
    f32x4 p0, p1;                                                            \
    _Pragma("unroll") for (int r = 0; r < 4; ++r) {                          \
      p0[r] = exp2f(st0[r] - m);                                             \
      p1[r] = exp2f(st1[r] - m);                                             \
    }                                                                        \
    lsum += ((p0[0] + p0[1]) + (p0[2] + p0[3])) +                            \
            ((p1[0] + p1[1]) + (p1[2] + p1[3]));                             \
    bf16x4 pb0, pb1;                                                         \
    _Pragma("unroll") for (int r = 0; r < 4; ++r) {                          \
      pb0[r] = (__bf16)p0[r];                                                \
      pb1[r] = (__bf16)p1[r];                                                \
    }                                                                        \
    const s16x4 pf0 = __builtin_bit_cast(s16x4, pb0);                        \
    const s16x4 pf1 = __builtin_bit_cast(s16x4, pb1);                        \
    oacc[0] = __builtin_amdgcn_mfma_f32_16x16x16bf16_1k(vv00, pf0, oacc[0], 0, 0, 0); \
    oacc[1] = __builtin_amdgcn_mfma_f32_16x16x16bf16_1k(vv01, pf0, oacc[1], 0, 0, 0); \
    oacc[2] = __builtin_amdgcn_mfma_f32_16x16x16bf16_1k(vv02, pf0, oacc[2], 0, 0, 0); \
    oacc[3] = __builtin_amdgcn_mfma_f32_16x16x16bf16_1k(vv03, pf0, oacc[3], 0, 0, 0); \
    oacc[0] = __builtin_amdgcn_mfma_f32_16x16x16bf16_1k(vv10, pf1, oacc[0], 0, 0, 0); \
    oacc[1] = __builtin_amdgcn_mfma_f32_16x16x16bf16_1k(vv11, pf1, oacc[1], 0, 0, 0); \
    oacc[2] = __builtin_amdgcn_mfma_f32_16x16x16bf16_1k(vv12, pf1, oacc[2], 0, 0, 0); \
    oacc[3] = __builtin_amdgcn_mfma_f32_16x16x16bf16_1k(vv13, pf1, oacc[3], 0, 0, 0); \
    ++j;                                                                     \
  }

__global__ __launch_bounds__(256) void attn_fwd3(
    const float* __restrict__ Qg, const short* __restrict__ Kb,
    const short* __restrict__ VTb, float* __restrict__ Og)
{
  const int tid  = threadIdx.x;
  const int lane = tid & 63;
  const int lm   = lane & 15;
  const int g    = lane >> 4;
  const int w    = tid >> 6;

  const int bh = blockIdx.x;  // 0..31
  const int t  = ((gridDim.y - 1 - blockIdx.y) << 2) | w;  // heavy-first
  const int qb = t << 4;

  const short* kbase = Kb  + (size_t)bh * SS * DD;
  const short* vtb   = VTb + (size_t)bh * DD * SS;
  const size_t qbase = (size_t)(bh >> 4) * SS * HSZ + (size_t)(bh & 15) * DD;

  // Q frag (B operand of S^T, K=32): d = c*32 + g*8 + j, pre-scaled
  s16x8 qf[2];
  {
    const float* qp = Qg + qbase + (size_t)(qb + lm) * HSZ + g * 8;
    const float qs = 0.125f * LOG2E;
#pragma unroll
    for (int c = 0; c < 2; ++c) {
      f32x4 a = *(const f32x4*)(qp + c * 32);
      f32x4 b2 = *(const f32x4*)(qp + c * 32 + 4);
      bf16x8 bv;
#pragma unroll
      for (int j2 = 0; j2 < 4; ++j2) {
        bv[j2] = (__bf16)(a[j2] * qs);
        bv[4 + j2] = (__bf16)(b2[j2] * qs);
      }
      qf[c] = __builtin_bit_cast(s16x8, bv);
    }
  }

  f32x4 oacc[4] = {{0,0,0,0},{0,0,0,0},{0,0,0,0},{0,0,0,0}};
  float m = -1e30f, lsum = 0.0f;

  const short* kp  = kbase + (size_t)lm * DD + g * 8;  // + key*64 per tile
  const short* vp0 = vtb + (size_t)lm * SS + g * 4;    // + nb*16*S + key

  const int ng = t >> 1;  // full 32-key groups over subtiles 0..2ng-1

  if (ng > 0) {
    s16x8 kA[4], kB[4];
    kA[0] = *(const s16x8*)(kp);
    kA[1] = *(const s16x8*)(kp + 32);
    kA[2] = *(const s16x8*)(kp + 16 * DD);
    kA[3] = *(const s16x8*)(kp + 16 * DD + 32);
    int j = 0;
    while (true) {
      GBODY(kA, kB)
      if (j >= ng) break;
      GBODY(kB, kA)
      if (j >= ng) break;
    }
  }

  // ---- tail: subtiles 2*ng .. t (1 or 2), diagonal mask on subtile t
  for (int sub = ng << 1; sub <= t; ++sub) {
    const short* kaT = kp + (size_t)sub * 16 * DD;
    f32x4 stv = {0, 0, 0, 0};
    stv = __builtin_amdgcn_mfma_f32_16x16x32_bf16(
        *(const s16x8*)(kaT), qf[0], stv, 0, 0, 0);
    stv = __builtin_amdgcn_mfma_f32_16x16x32_bf16(
        *(const s16x8*)(kaT + 32), qf[1], stv, 0, 0, 0);
    if (sub == t) {
#pragma unroll
      for (int r = 0; r < 4; ++r)
        if (g * 4 + r > lm) stv[r] = -1e30f;
    }
    float tmax = fmaxf(fmaxf(stv[0], stv[1]), fmaxf(stv[2], stv[3]));
    if (!__all(tmax <= m + 8.0f)) {
      float tm = fmaxf(tmax, __shfl_xor(tmax, 16));
      tm = fmaxf(tm, __shfl_xor(tm, 32));
      const float mnew = fmaxf(m, tm);
      const float fsc = exp2f(m - mnew);
#pragma unroll
      for (int nb = 0; nb < 4; ++nb)
#pragma unroll
        for (int r = 0; r < 4; ++r) oacc[nb][r] *= fsc;
      lsum *= fsc;
      m = mnew;
    }
    f32x4 p;
#pragma unroll
    for (int r = 0; r < 4; ++r) p[r] = exp2f(stv[r] - m);
    lsum += (p[0] + p[1]) + (p[2] + p[3]);
    bf16x4 pb;
#pragma unroll
    for (int r = 0; r < 4; ++r) pb[r] = (__bf16)p[r];
    const s16x4 pf = __builtin_bit_cast(s16x4, pb);
    const short* vpp = vp0 + (sub << 4);
#pragma unroll
    for (int nb = 0; nb < 4; ++nb) {
      s16x4 vv = *(const s16x4*)(vpp + (size_t)nb * 16 * SS);
      oacc[nb] = __builtin_amdgcn_mfma_f32_16x16x16bf16_1k(
          vv, pf, oacc[nb], 0, 0, 0);
    }
  }

  // ---- epilogue: reduce l across the 4 g-lanes, normalize, store
  float l = lsum;
  l += __shfl_xor(l, 16);
  l += __shfl_xor(l, 32);
  const float inv = 1.0f / l;
  float* op = Og + qbase + (size_t)(qb + lm) * HSZ + g * 4;
#pragma unroll
  for (int nb = 0; nb < 4; ++nb) {
    f32x4 o = oacc[nb];
#pragma unroll
    for (int r = 0; r < 4; ++r) o[r] *= inv;
    *(f32x4*)(op + nb * 16) = o;
  }
}

// ---- fallback (round-1 kernel) if ws too small ---------------------------
__global__ __launch_bounds__(256) void attn_fwd(
    const float* __restrict__ Qg, const float* __restrict__ Kg,
    const float* __restrict__ Vg, float* __restrict__ Og)
{
  const int tid  = threadIdx.x;
  const int lane = tid & 63;
  const int lm   = lane & 15;
  const int g    = lane >> 4;
  const int w    = tid >> 6;
  const int bh = blockIdx.x;
  const int b  = bh >> 4;
  const int h  = bh & 15;
  const int t  = ((gridDim.y - 1 - blockIdx.y) << 2) | w;
  const int qb = t << 4;
  const size_t base = (size_t)b * SS * HSZ + (size_t)h * DD;
  s16x4 qf[4];
  {
    const float* qp = Qg + base + (size_t)(qb + lm) * HSZ + g * 4;
    const float qs = 0.125f * LOG2E;
#pragma unroll
    for (int c = 0; c < 4; ++c) {
      f32x4 qv = *(const f32x4*)(qp + c * 16);
      bf16x4 bv;
#pragma unroll
      for (int j = 0; j < 4; ++j) bv[j] = (__bf16)(qv[j] * qs);
      qf[c] = __builtin_bit_cast(s16x4, bv);
    }
  }
  f32x4 oacc[4] = {{0,0,0,0},{0,0,0,0},{0,0,0,0},{0,0,0,0}};
  float m = -1e30f, lsum = 0.0f;
  const float* kp = Kg + base + (size_t)lm * HSZ + g * 4;
  const float* vp = Vg + base + (size_t)(g * 4) * HSZ + lm;
  for (int kt = 0; kt <= t; ++kt) {
    const float* kpp = kp + (size_t)(kt << 4) * HSZ;
    f32x4 st = {0, 0, 0, 0};
#pragma unroll
    for (int c = 0; c < 4; ++c) {
      f32x4 kv = *(const f32x4*)(kpp + c * 16);
      bf16x4 bv;
#pragma unroll
      for (int j = 0; j < 4; ++j) bv[j] = (__bf16)kv[j];
      st = __builtin_amdgcn_mfma_f32_16x16x16bf16_1k(
               __builtin_bit_cast(s16x4, bv), qf[c], st, 0, 0, 0);
    }
    if (kt == t) {
#pragma unroll
      for (int r = 0; r < 4; ++r)
        if (g * 4 + r > lm) st[r] = -1e30f;
    }
    float tmax = fmaxf(fmaxf(st[0], st[1]), fmaxf(st[2], st[3]));
    tmax = fmaxf(tmax, __shfl_xor(tmax, 16));
    tmax = fmaxf(tmax, __shfl_xor(tmax, 32));
    const float mnew = fmaxf(m, tmax);
    const float fsc  = exp2f(m - mnew);
    f32x4 p;
#pragma unroll
    for (int r = 0; r < 4; ++r) p[r] = exp2f(st[r] - mnew);
    float tsum = (p[0] + p[1]) + (p[2] + p[3]);
    tsum += __shfl_xor(tsum, 16);
    tsum += __shfl_xor(tsum, 32);
    lsum = lsum * fsc + tsum;
    m = mnew;
#pragma unroll
    for (int nb = 0; nb < 4; ++nb)
#pragma unroll
      for (int r = 0; r < 4; ++r) oacc[nb][r] *= fsc;
    bf16x4 pb;
#pragma unroll
    for (int r = 0; r < 4; ++r) pb[r] = (__bf16)p[r];
    const s16x4 pf = __builtin_bit_cast(s16x4, pb);
    const float* vpp = vp + (size_t)(kt << 4) * HSZ;
#pragma unroll
    for (int nb = 0; nb < 4; ++nb) {
      bf16x4 vv;
#pragma unroll
      for (int j = 0; j < 4; ++j)
        vv[j] = (__bf16)vpp[(size_t)j * HSZ + nb * 16];
      oacc[nb] = __builtin_amdgcn_mfma_f32_16x16x16bf16_1k(
                     __builtin_bit_cast(s16x4, vv), pf, oacc[nb], 0, 0, 0);
    }
  }
  const float inv = 1.0f / lsum;
  float* op = Og + base + (size_t)(qb + lm) * HSZ + g * 4;
#pragma unroll
  for (int nb = 0; nb < 4; ++nb) {
    f32x4 o = oacc[nb];
#pragma unroll
    for (int r = 0; r < 4; ++r) o[r] *= inv;
    *(f32x4*)(op + nb * 16) = o;
  }
}

extern "C" void kernel_launch(void* const* d_in, const int* in_sizes, int n_in,
                              void* d_out, int out_size, void* d_ws, size_t ws_size,
                              hipStream_t stream) {
  const float* q = (const float*)d_in[0];
  const float* k = (const float*)d_in[1];
  const float* v = (const float*)d_in[2];
  float* o = (float*)d_out;
  const size_t elems = (size_t)2 * HH * SS * DD;     // 4,194,304 per tensor
  const size_t need  = 2 * elems * sizeof(short);    // Kb + VT, 16.8 MB
  if (ws_size >= need) {
    short* Kb = (short*)d_ws;
    short* VT = Kb + elems;
    prep_k<<<4096, 256, 0, stream>>>(k, Kb);
    prep_vt<<<1024, 256, 0, stream>>>(v, VT);
    attn_fwd3<<<dim3(32, 32), 256, 0, stream>>>(q, Kb, VT, o);
  } else {
    attn_fwd<<<dim3(32, 32), 256, 0, stream>>>(q, k, v, o);
  }
}

// Round 4
// 76.134 us; speedup vs baseline: 2.9769x; 2.8040x over previous
//
#include <hip/hip_runtime.h>

#define LOG2E 1.4426950408889634f

typedef __attribute__((ext_vector_type(4))) float f32x4;
typedef __attribute__((ext_vector_type(4))) short s16x4;
typedef __attribute__((ext_vector_type(8))) short s16x8;
typedef __attribute__((ext_vector_type(4))) __bf16 bf16x4;
typedef __attribute__((ext_vector_type(8))) __bf16 bf16x8;

// B=2 S=2048 H=16 D=64, fp32 in/out.
#define SS 2048
#define HH 16
#define DD 64
#define HSZ (HH * DD)
#define BHSZ (SS * DD)  // 131072 elems per (b,h) plane

// ---- prep 1: K [B,S,H,D] f32 -> Kf fragment-major bf16 -------------------
// Kf[bh][subtile s][c][lane][j]: lane l -> K[key=s*16+(l&15)][d=c*32+(l>>4)*8+j]
// One thread = one 16B output chunk; writes fully coalesced.
__global__ __launch_bounds__(256) void prep_k2(const float* __restrict__ Kg,
                                               short* __restrict__ Kf) {
  const int idx = blockIdx.x * 256 + threadIdx.x;  // 524,288 chunks
  const int l  = idx & 63;
  const int c  = (idx >> 6) & 1;
  const int s  = (idx >> 7) & 127;
  const int bh = idx >> 14;
  const int b = bh >> 4, h = bh & 15;
  const int key = (s << 4) + (l & 15);
  const int d0  = (c << 5) + ((l >> 4) << 3);
  const float* src = Kg + (((size_t)b * SS + key) * HH + h) * DD + d0;
  f32x4 a = *(const f32x4*)(src);
  f32x4 b2 = *(const f32x4*)(src + 4);
  bf16x8 o;
#pragma unroll
  for (int j = 0; j < 4; ++j) {
    o[j] = (__bf16)a[j];
    o[4 + j] = (__bf16)b2[j];
  }
  *(s16x8*)(Kf + (size_t)idx * 8) = __builtin_bit_cast(s16x8, o);
}

// ---- prep 2: V [B,S,H,D] f32 -> Vf fragment-major bf16 -------------------
// Vf[bh][subtile s][nb][lane][j]: lane l -> V[key=s*16+(l>>4)*4+j][d=nb*16+(l&15)]
__global__ __launch_bounds__(256) void prep_v2(const float* __restrict__ Vg,
                                               short* __restrict__ Vf) {
  const int idx = blockIdx.x * 256 + threadIdx.x;  // 1,048,576 chunks
  const int l  = idx & 63;
  const int nb = (idx >> 6) & 3;
  const int s  = (idx >> 8) & 127;
  const int bh = idx >> 15;
  const int b = bh >> 4, h = bh & 15;
  const int d    = (nb << 4) + (l & 15);
  const int key0 = (s << 4) + ((l >> 4) << 2);
  const float* src = Vg + (((size_t)b * SS + key0) * HH + h) * DD + d;
  bf16x4 o;
#pragma unroll
  for (int j = 0; j < 4; ++j) o[j] = (__bf16)src[(size_t)j * HSZ];
  *(s16x4*)(Vf + (size_t)idx * 4) = __builtin_bit_cast(s16x4, o);
}

// ---- main: flash attention, fragment-major K/V, coalesced loads ----------
// One wave per 16 q-rows. S^T = K*Q^T (16x16x32) so P registers feed PV's
// B operand (OT = V^T*P, 16x16x16) with zero cross-lane traffic.
// All hot-loop loads are base + lane*16B (K) / lane*8B (V): 1-2 L2
// transactions each (was ~16 when reading strided [S,D]/[D,S] layouts).
// 32-key groups; K reg-double-buffered; vote-deferred softmax (THR=8 in
// log2 -> P <= 256), l reduced once in the epilogue.
#define GBODY(KC, KN)                                                        \
  {                                                                          \
    const short* vj = vb2 + ((size_t)j << 11);                               \
    s16x4 vv00 = *(const s16x4*)(vj);                                        \
    s16x4 vv01 = *(const s16x4*)(vj + 256);                                  \
    s16x4 vv02 = *(const s16x4*)(vj + 512);                                  \
    s16x4 vv03 = *(const s16x4*)(vj + 768);                                  \
    s16x4 vv10 = *(const s16x4*)(vj + 1024);                                 \
    s16x4 vv11 = *(const s16x4*)(vj + 1280);                                 \
    s16x4 vv12 = *(const s16x4*)(vj + 1536);                                 \
    s16x4 vv13 = *(const s16x4*)(vj + 1792);                                 \
    const int jn = (j + 1 < ng) ? j + 1 : j;                                 \
    const short* kn = kb2 + ((size_t)jn << 11);                              \
    KN[0] = *(const s16x8*)(kn);                                             \
    KN[1] = *(const s16x8*)(kn + 512);                                       \
    KN[2] = *(const s16x8*)(kn + 1024);                                      \
    KN[3] = *(const s16x8*)(kn + 1536);                                      \
    f32x4 st0 = {0, 0, 0, 0}, st1 = {0, 0, 0, 0};                            \
    st0 = __builtin_amdgcn_mfma_f32_16x16x32_bf16(KC[0], qf[0], st0, 0, 0, 0);\
    st0 = __builtin_amdgcn_mfma_f32_16x16x32_bf16(KC[1], qf[1], st0, 0, 0, 0);\
    st1 = __builtin_amdgcn_mfma_f32_16x16x32_bf16(KC[2], qf[0], st1, 0, 0, 0);\
    st1 = __builtin_amdgcn_mfma_f32_16x16x32_bf16(KC[3], qf[1], st1, 0, 0, 0);\
    float tmax = fmaxf(fmaxf(fmaxf(st0[0], st0[1]), fmaxf(st0[2], st0[3])),  \
                       fmaxf(fmaxf(st1[0], st1[1]), fmaxf(st1[2], st1[3]))); \
    if (!__all(tmax <= m + 8.0f)) {                                          \
      float tm = fmaxf(tmax, __shfl_xor(tmax, 16));                          \
      tm = fmaxf(tm, __shfl_xor(tm, 32));                                    \
      const float mnew = fmaxf(m, tm);                                       \
      const float fsc = exp2f(m - mnew);                                     \
      _Pragma("unroll") for (int nb = 0; nb < 4; ++nb)                       \
          _Pragma("unroll") for (int r = 0; r < 4; ++r) oacc[nb][r] *= fsc;  \
      lsum *= fsc;                                                           \
      m = mnew;                                                              \
    }                                                                        \
    f32x4 p0, p1;                                                            \
    _Pragma("unroll") for (int r = 0; r < 4; ++r) {                          \
      p0[r] = exp2f(st0[r] - m);                                             \
      p1[r] = exp2f(st1[r] - m);                                             \
    }                                                                        \
    lsum += ((p0[0] + p0[1]) + (p0[2] + p0[3])) +                            \
            ((p1[0] + p1[1]) + (p1[2] + p1[3]));                             \
    bf16x4 pb0, pb1;                                                         \
    _Pragma("unroll") for (int r = 0; r < 4; ++r) {                          \
      pb0[r] = (__bf16)p0[r];                                                \
      pb1[r] = (__bf16)p1[r];                                                \
    }                                                                        \
    const s16x4 pf0 = __builtin_bit_cast(s16x4, pb0);                        \
    const s16x4 pf1 = __builtin_bit_cast(s16x4, pb1);                        \
    oacc[0] = __builtin_amdgcn_mfma_f32_16x16x16bf16_1k(vv00, pf0, oacc[0], 0, 0, 0); \
    oacc[1] = __builtin_amdgcn_mfma_f32_16x16x16bf16_1k(vv01, pf0, oacc[1], 0, 0, 0); \
    oacc[2] = __builtin_amdgcn_mfma_f32_16x16x16bf16_1k(vv02, pf0, oacc[2], 0, 0, 0); \
    oacc[3] = __builtin_amdgcn_mfma_f32_16x16x16bf16_1k(vv03, pf0, oacc[3], 0, 0, 0); \
    oacc[0] = __builtin_amdgcn_mfma_f32_16x16x16bf16_1k(vv10, pf1, oacc[0], 0, 0, 0); \
    oacc[1] = __builtin_amdgcn_mfma_f32_16x16x16bf16_1k(vv11, pf1, oacc[1], 0, 0, 0); \
    oacc[2] = __builtin_amdgcn_mfma_f32_16x16x16bf16_1k(vv12, pf1, oacc[2], 0, 0, 0); \
    oacc[3] = __builtin_amdgcn_mfma_f32_16x16x16bf16_1k(vv13, pf1, oacc[3], 0, 0, 0); \
    ++j;                                                                     \
  }

__global__ __launch_bounds__(256) void attn_fwd4(
    const float* __restrict__ Qg, const short* __restrict__ Kf,
    const short* __restrict__ Vf, float* __restrict__ Og)
{
  const int tid  = threadIdx.x;
  const int lane = tid & 63;
  const int lm   = lane & 15;
  const int g    = lane >> 4;
  const int w    = tid >> 6;

  const int bh = blockIdx.x;  // 0..31
  const int t  = ((gridDim.y - 1 - blockIdx.y) << 2) | w;  // heavy-first
  const int qb = t << 4;

  const size_t qbase = (size_t)(bh >> 4) * SS * HSZ + (size_t)(bh & 15) * DD;
  const short* kb2 = Kf + (size_t)bh * BHSZ + lane * 8;
  const short* vb2 = Vf + (size_t)bh * BHSZ + lane * 4;

  // Q frag (B operand of S^T, K=32): d = c*32 + g*8 + j, pre-scaled
  s16x8 qf[2];
  {
    const float* qp = Qg + qbase + (size_t)(qb + lm) * HSZ + g * 8;
    const float qs = 0.125f * LOG2E;
#pragma unroll
    for (int c = 0; c < 2; ++c) {
      f32x4 a = *(const f32x4*)(qp + c * 32);
      f32x4 b2 = *(const f32x4*)(qp + c * 32 + 4);
      bf16x8 bv;
#pragma unroll
      for (int j2 = 0; j2 < 4; ++j2) {
        bv[j2] = (__bf16)(a[j2] * qs);
        bv[4 + j2] = (__bf16)(b2[j2] * qs);
      }
      qf[c] = __builtin_bit_cast(s16x8, bv);
    }
  }

  f32x4 oacc[4] = {{0,0,0,0},{0,0,0,0},{0,0,0,0},{0,0,0,0}};
  float m = -1e30f, lsum = 0.0f;

  const int ng = t >> 1;  // full 32-key groups over subtiles 0..2ng-1

  if (ng > 0) {
    s16x8 kA[4], kB[4];
    kA[0] = *(const s16x8*)(kb2);
    kA[1] = *(const s16x8*)(kb2 + 512);
    kA[2] = *(const s16x8*)(kb2 + 1024);
    kA[3] = *(const s16x8*)(kb2 + 1536);
    int j = 0;
    while (true) {
      GBODY(kA, kB)
      if (j >= ng) break;
      GBODY(kB, kA)
      if (j >= ng) break;
    }
  }

  // ---- tail: subtiles 2*ng .. t (1 or 2), diagonal mask on subtile t
  for (int sub = ng << 1; sub <= t; ++sub) {
    const short* kaT = kb2 + ((size_t)sub << 10);
    f32x4 stv = {0, 0, 0, 0};
    stv = __builtin_amdgcn_mfma_f32_16x16x32_bf16(
        *(const s16x8*)(kaT), qf[0], stv, 0, 0, 0);
    stv = __builtin_amdgcn_mfma_f32_16x16x32_bf16(
        *(const s16x8*)(kaT + 512), qf[1], stv, 0, 0, 0);
    if (sub == t) {
#pragma unroll
      for (int r = 0; r < 4; ++r)
        if (g * 4 + r > lm) stv[r] = -1e30f;
    }
    float tmax = fmaxf(fmaxf(stv[0], stv[1]), fmaxf(stv[2], stv[3]));
    if (!__all(tmax <= m + 8.0f)) {
      float tm = fmaxf(tmax, __shfl_xor(tmax, 16));
      tm = fmaxf(tm, __shfl_xor(tm, 32));
      const float mnew = fmaxf(m, tm);
      const float fsc = exp2f(m - mnew);
#pragma unroll
      for (int nb = 0; nb < 4; ++nb)
#pragma unroll
        for (int r = 0; r < 4; ++r) oacc[nb][r] *= fsc;
      lsum *= fsc;
      m = mnew;
    }
    f32x4 p;
#pragma unroll
    for (int r = 0; r < 4; ++r) p[r] = exp2f(stv[r] - m);
    lsum += (p[0] + p[1]) + (p[2] + p[3]);
    bf16x4 pb;
#pragma unroll
    for (int r = 0; r < 4; ++r) pb[r] = (__bf16)p[r];
    const s16x4 pf = __builtin_bit_cast(s16x4, pb);
    const short* vpp = vb2 + ((size_t)sub << 10);
#pragma unroll
    for (int nb = 0; nb < 4; ++nb) {
      s16x4 vv = *(const s16x4*)(vpp + nb * 256);
      oacc[nb] = __builtin_amdgcn_mfma_f32_16x16x16bf16_1k(
          vv, pf, oacc[nb], 0, 0, 0);
    }
  }

  // ---- epilogue: reduce l across the 4 g-lanes, normalize, store
  float l = lsum;
  l += __shfl_xor(l, 16);
  l += __shfl_xor(l, 32);
  const float inv = 1.0f / l;
  float* op = Og + qbase + (size_t)(qb + lm) * HSZ + g * 4;
#pragma unroll
  for (int nb = 0; nb < 4; ++nb) {
    f32x4 o = oacc[nb];
#pragma unroll
    for (int r = 0; r < 4; ++r) o[r] *= inv;
    *(f32x4*)(op + nb * 16) = o;
  }
}

// ---- fallback (round-1 kernel) if ws too small ---------------------------
__global__ __launch_bounds__(256) void attn_fwd(
    const float* __restrict__ Qg, const float* __restrict__ Kg,
    const float* __restrict__ Vg, float* __restrict__ Og)
{
  const int tid  = threadIdx.x;
  const int lane = tid & 63;
  const int lm   = lane & 15;
  const int g    = lane >> 4;
  const int w    = tid >> 6;
  const int bh = blockIdx.x;
  const int b  = bh >> 4;
  const int h  = bh & 15;
  const int t  = ((gridDim.y - 1 - blockIdx.y) << 2) | w;
  const int qb = t << 4;
  const size_t base = (size_t)b * SS * HSZ + (size_t)h * DD;
  s16x4 qf[4];
  {
    const float* qp = Qg + base + (size_t)(qb + lm) * HSZ + g * 4;
    const float qs = 0.125f * LOG2E;
#pragma unroll
    for (int c = 0; c < 4; ++c) {
      f32x4 qv = *(const f32x4*)(qp + c * 16);
      bf16x4 bv;
#pragma unroll
      for (int j = 0; j < 4; ++j) bv[j] = (__bf16)(qv[j] * qs);
      qf[c] = __builtin_bit_cast(s16x4, bv);
    }
  }
  f32x4 oacc[4] = {{0,0,0,0},{0,0,0,0},{0,0,0,0},{0,0,0,0}};
  float m = -1e30f, lsum = 0.0f;
  const float* kp = Kg + base + (size_t)lm * HSZ + g * 4;
  const float* vp = Vg + base + (size_t)(g * 4) * HSZ + lm;
  for (int kt = 0; kt <= t; ++kt) {
    const float* kpp = kp + (size_t)(kt << 4) * HSZ;
    f32x4 st = {0, 0, 0, 0};
#pragma unroll
    for (int c = 0; c < 4; ++c) {
      f32x4 kv = *(const f32x4*)(kpp + c * 16);
      bf16x4 bv;
#pragma unroll
      for (int j = 0; j < 4; ++j) bv[j] = (__bf16)kv[j];
      st = __builtin_amdgcn_mfma_f32_16x16x16bf16_1k(
               __builtin_bit_cast(s16x4, bv), qf[c], st, 0, 0, 0);
    }
    if (kt == t) {
#pragma unroll
      for (int r = 0; r < 4; ++r)
        if (g * 4 + r > lm) st[r] = -1e30f;
    }
    float tmax = fmaxf(fmaxf(st[0], st[1]), fmaxf(st[2], st[3]));
    tmax = fmaxf(tmax, __shfl_xor(tmax, 16));
    tmax = fmaxf(tmax, __shfl_xor(tmax, 32));
    const float mnew = fmaxf(m, tmax);
    const float fsc  = exp2f(m - mnew);
    f32x4 p;
#pragma unroll
    for (int r = 0; r < 4; ++r) p[r] = exp2f(st[r] - mnew);
    float tsum = (p[0] + p[1]) + (p[2] + p[3]);
    tsum += __shfl_xor(tsum, 16);
    tsum += __shfl_xor(tsum, 32);
    lsum = lsum * fsc + tsum;
    m = mnew;
#pragma unroll
    for (int nb = 0; nb < 4; ++nb)
#pragma unroll
      for (int r = 0; r < 4; ++r) oacc[nb][r] *= fsc;
    bf16x4 pb;
#pragma unroll
    for (int r = 0; r < 4; ++r) pb[r] = (__bf16)p[r];
    const s16x4 pf = __builtin_bit_cast(s16x4, pb);
    const float* vpp = vp + (size_t)(kt << 4) * HSZ;
#pragma unroll
    for (int nb = 0; nb < 4; ++nb) {
      bf16x4 vv;
#pragma unroll
      for (int j = 0; j < 4; ++j)
        vv[j] = (__bf16)vpp[(size_t)j * HSZ + nb * 16];
      oacc[nb] = __builtin_amdgcn_mfma_f32_16x16x16bf16_1k(
                     __builtin_bit_cast(s16x4, vv), pf, oacc[nb], 0, 0, 0);
    }
  }
  const float inv = 1.0f / lsum;
  float* op = Og + base + (size_t)(qb + lm) * HSZ + g * 4;
#pragma unroll
  for (int nb = 0; nb < 4; ++nb) {
    f32x4 o = oacc[nb];
#pragma unroll
    for (int r = 0; r < 4; ++r) o[r] *= inv;
    *(f32x4*)(op + nb * 16) = o;
  }
}

extern "C" void kernel_launch(void* const* d_in, const int* in_sizes, int n_in,
                              void* d_out, int out_size, void* d_ws, size_t ws_size,
                              hipStream_t stream) {
  const float* q = (const float*)d_in[0];
  const float* k = (const float*)d_in[1];
  const float* v = (const float*)d_in[2];
  float* o = (float*)d_out;
  const size_t elems = (size_t)2 * HH * SS * DD;     // 4,194,304 per tensor
  const size_t need  = 2 * elems * sizeof(short);    // Kf + Vf, 16.8 MB
  if (ws_size >= need) {
    short* Kf = (short*)d_ws;
    short* Vf = Kf + elems;
    prep_k2<<<2048, 256, 0, stream>>>(k, Kf);
    prep_v2<<<4096, 256, 0, stream>>>(v, Vf);
    attn_fwd4<<<dim3(32, 32), 256, 0, stream>>>(q, Kf, Vf, o);
  } else {
    attn_fwd<<<dim3(32, 32), 256, 0, stream>>>(q, k, v, o);
  }
}